// Round 1
// baseline (64.453 us; speedup 1.0000x reference)
//
#include <hip/hip_runtime.h>

#define NQ 15

// Apply RY(gate=[[c,-s],[s,c]]) on window bit T of the 32-dim state.
template<int T>
__device__ inline void apply_ry(float (&re)[32], float (&im)[32], float cg, float sg) {
#pragma unroll
    for (int x = 0; x < 32; x++) {
        if (!(x & (1 << T))) {
            const int y = x | (1 << T);
            float r0 = re[x], i0 = im[x], r1 = re[y], i1 = im[y];
            re[x] = cg * r0 - sg * r1;
            im[x] = cg * i0 - sg * i1;
            re[y] = sg * r0 + cg * r1;
            im[y] = sg * i0 + cg * i1;
        }
    }
}

// CZ on window bits (T,U): flip sign where both bits set.
template<int T, int U>
__device__ inline void apply_cz(float (&re)[32], float (&im)[32]) {
#pragma unroll
    for (int x = 0; x < 32; x++) {
        if (((x >> T) & 1) && ((x >> U) & 1)) { re[x] = -re[x]; im[x] = -im[x]; }
    }
}

__global__ __launch_bounds__(256)
void HybridRegression_lightcone_kernel(const float* __restrict__ sb,    // (B, 15)
                                       const float* __restrict__ theta, // (45,)
                                       const float* __restrict__ hw,    // (1,15)
                                       const float* __restrict__ hb,    // (1,)
                                       float* __restrict__ out,         // (B,)
                                       int batch) {
    const int wave = threadIdx.x >> 6;   // 4 waves per block, one batch elem each
    const int lane = threadIdx.x & 63;
    const int b = blockIdx.x * 4 + wave;

    float contrib = 0.0f;

    if (b < batch && lane < NQ) {
        const int q = lane;

        // ---- prep: product state of RX(a_j)|0> over window qubits j=q-2..q+2 ----
        // RX factor per qubit: amp(bit=0)=cos(a/2), amp(bit=1)=-i*sin(a/2).
        float pc[5], ps[5];
#pragma unroll
        for (int w = 0; w < 5; w++) {
            const int j = q - 2 + w;
            const float a = (j >= 0 && j < NQ) ? sb[b * NQ + j] : 0.0f;
            const float h = 0.5f * a;
            pc[w] = cosf(h);
            ps[w] = sinf(h);
        }

        float re[32], im[32];
        re[0] = 1.0f; im[0] = 0.0f;
#pragma unroll
        for (int w = 0; w < 5; w++) {
#pragma unroll
            for (int x = 0; x < 16; x++) {
                if (x < (1 << w)) {
                    const int y = x + (1 << w);
                    // amp[y] = amp[x] * (-i * s)
                    re[y] =  im[x] * ps[w];
                    im[y] = -re[x] * ps[w];
                    re[x] *= pc[w];
                    im[x] *= pc[w];
                }
            }
        }

        // ---- gate angles (half-angles), zero-padded outside [0,15) ----
        float c1[5], s1[5];
#pragma unroll
        for (int w = 0; w < 5; w++) {
            const int j = q - 2 + w;
            const float th = (j >= 0 && j < NQ) ? theta[0 * NQ + j] : 0.0f;
            c1[w] = cosf(0.5f * th);
            s1[w] = sinf(0.5f * th);
        }
        float c2[3], s2[3];
#pragma unroll
        for (int w = 0; w < 3; w++) {
            const int j = q - 1 + w;
            const float th = (j >= 0 && j < NQ) ? theta[1 * NQ + j] : 0.0f;
            c2[w] = cosf(0.5f * th);
            s2[w] = sinf(0.5f * th);
        }
        const float th3 = theta[2 * NQ + q];
        const float c3 = cosf(0.5f * th3), s3 = sinf(0.5f * th3);

        // ---- layer 1: RY on all 5 window qubits, then CZ chain (4 pairs) ----
        apply_ry<0>(re, im, c1[0], s1[0]);
        apply_ry<1>(re, im, c1[1], s1[1]);
        apply_ry<2>(re, im, c1[2], s1[2]);
        apply_ry<3>(re, im, c1[3], s1[3]);
        apply_ry<4>(re, im, c1[4], s1[4]);
        apply_cz<0, 1>(re, im);
        apply_cz<1, 2>(re, im);
        apply_cz<2, 3>(re, im);
        apply_cz<3, 4>(re, im);

        // ---- layer 2: RY on window bits 1..3 (qubits q-1..q+1), CZ (1,2),(2,3) ----
        apply_ry<1>(re, im, c2[0], s2[0]);
        apply_ry<2>(re, im, c2[1], s2[1]);
        apply_ry<3>(re, im, c2[2], s2[2]);
        apply_cz<1, 2>(re, im);
        apply_cz<2, 3>(re, im);

        // ---- layer 3: RY on center bit only (rest of layer 3 is outside light cone) ----
        apply_ry<2>(re, im, c3, s3);

        // ---- <Z_q> = sum |amp|^2 * (+1 if center bit 0 else -1) ----
        float zq = 0.0f;
#pragma unroll
        for (int x = 0; x < 32; x++) {
            const float p = re[x] * re[x] + im[x] * im[x];
            zq += (x & 4) ? -p : p;
        }

        // head: out[b] = sum_q head_w[14-q] * <Z_q> + head_b
        contrib = hw[(NQ - 1) - q] * zq;
    }

    // wave-wide butterfly reduction (lanes >= 15 contribute 0)
#pragma unroll
    for (int off = 32; off >= 1; off >>= 1)
        contrib += __shfl_xor(contrib, off, 64);

    if (lane == 0 && b < batch)
        out[b] = contrib + hb[0];
}

extern "C" void kernel_launch(void* const* d_in, const int* in_sizes, int n_in,
                              void* d_out, int out_size, void* d_ws, size_t ws_size,
                              hipStream_t stream) {
    const float* sb    = (const float*)d_in[0]; // state_batch (512,15)
    const float* theta = (const float*)d_in[1]; // (45,)
    const float* hw    = (const float*)d_in[2]; // (1,15)
    const float* hb    = (const float*)d_in[3]; // (1,)
    float* out = (float*)d_out;                 // (512,) fp32

    const int batch = in_sizes[0] / NQ;
    const int blocks = (batch + 3) / 4; // 4 batch elems (waves) per 256-thread block

    hipLaunchKernelGGL(HybridRegression_lightcone_kernel,
                       dim3(blocks), dim3(256), 0, stream,
                       sb, theta, hw, hb, out, batch);
}

// Round 2
// 61.884 us; speedup vs baseline: 1.0415x; 1.0415x over previous
//
#include <hip/hip_runtime.h>

#define NQ 15

// RY([[c,-s],[s,c]]) on window bit T of the 32-dim state.
template<int T>
__device__ inline void apply_ry(float (&re)[32], float (&im)[32], float cg, float sg) {
#pragma unroll
    for (int x = 0; x < 32; x++) {
        if (!(x & (1 << T))) {
            const int y = x | (1 << T);
            float r0 = re[x], i0 = im[x], r1 = re[y], i1 = im[y];
            re[x] = cg * r0 - sg * r1;
            im[x] = cg * i0 - sg * i1;
            re[y] = sg * r0 + cg * r1;
            im[y] = sg * i0 + cg * i1;
        }
    }
}

__global__ __launch_bounds__(256)
void HybridRegression_lightcone2_kernel(const float* __restrict__ sb,    // (B,15)
                                        const float* __restrict__ theta, // (45,)
                                        const float* __restrict__ hw,    // (1,15)
                                        const float* __restrict__ hb,    // (1,)
                                        float* __restrict__ out,         // (B,)
                                        int batch) {
    const int wave = threadIdx.x >> 6;   // 4 waves/block, one batch elem per wave
    const int lane = threadIdx.x & 63;
    int b = blockIdx.x * 4 + wave;
    const bool bv = (b < batch);
    if (!bv) b = batch - 1;              // clamp for safe loads; store is guarded

    const int q = lane;
    const bool qv = (q < NQ);

    // Own angles (zero outside range -> identity factors; lanes 15..63 hold identity)
    const float a  = qv ? sb[b * NQ + q]    : 0.0f;
    const float t1 = qv ? theta[q]          : 0.0f;
    const float t2 = qv ? theta[NQ + q]     : 0.0f;
    const float t3 = qv ? theta[2 * NQ + q] : 0.0f;

    float sh, ch;  sincosf(0.5f * a,  &sh, &ch);
    float s1, c1;  sincosf(0.5f * t1, &s1, &c1);
    float s2, c2;  sincosf(0.5f * t2, &s2, &c2);
    float s3, c3;  sincosf(t3,        &s3, &c3);  // FULL angle: fused into measurement

    // Combined RX(a)·RY(t1)|0> per-qubit factor: (x0+i y0)|0> + (x1+i y1)|1>
    const float x0 = c1 * ch, y0 = s1 * sh;
    const float x1 = s1 * ch, y1 = -c1 * sh;

    // Gather window factors (qubits q-2..q+2) from neighbor lanes.
    // Out-of-range -> lane 15, which holds the zero-angle identity (1,0,0,0).
    float fx0[5], fy0[5], fx1[5], fy1[5];
#pragma unroll
    for (int w = 0; w < 5; w++) {
        const int j = q - 2 + w;
        const int src = (j >= 0 && j < NQ) ? j : NQ;
        fx0[w] = __shfl(x0, src, 64);
        fy0[w] = __shfl(y0, src, 64);
        fx1[w] = __shfl(x1, src, 64);
        fy1[w] = __shfl(y1, src, 64);
    }
    float g2c[3], g2s[3];
#pragma unroll
    for (int w = 0; w < 3; w++) {
        const int j = q - 1 + w;
        const int src = (j >= 0 && j < NQ) ? j : NQ;
        g2c[w] = __shfl(c2, src, 64);
        g2s[w] = __shfl(s2, src, 64);
    }

    // Build the 5-qubit product state (already includes layer-1 RY).
    float re[32], im[32];
    re[0] = fx0[0]; im[0] = fy0[0];
    re[1] = fx1[0]; im[1] = fy1[0];
#pragma unroll
    for (int w = 1; w < 5; w++) {
#pragma unroll
        for (int x = 0; x < 16; x++) {
            if (x < (1 << w)) {
                const int y = x + (1 << w);
                const float r = re[x], i = im[x];
                re[y] = r * fx1[w] - i * fy1[w];
                im[y] = r * fy1[w] + i * fx1[w];
                re[x] = r * fx0[w] - i * fy0[w];
                im[x] = r * fy0[w] + i * fx0[w];
            }
        }
    }

    // Layer-1 CZ chain (0,1)(1,2)(2,3)(3,4), folded into one constexpr sign pass.
#pragma unroll
    for (int x = 0; x < 32; x++) {
        const int p = (((x >> 0) & 3) == 3) + (((x >> 1) & 3) == 3)
                    + (((x >> 2) & 3) == 3) + (((x >> 3) & 3) == 3);
        if (p & 1) { re[x] = -re[x]; im[x] = -im[x]; }
    }

    // Layer-2 RY on window bits 1..3 (qubits q-1..q+1).
    apply_ry<1>(re, im, g2c[0], g2s[0]);
    apply_ry<2>(re, im, g2c[1], g2s[1]);
    apply_ry<3>(re, im, g2c[2], g2s[2]);

    // Layer-2 CZ (1,2)(2,3), folded.
#pragma unroll
    for (int x = 0; x < 32; x++) {
        const int p = (((x >> 1) & 3) == 3) + (((x >> 2) & 3) == 3);
        if (p & 1) { re[x] = -re[x]; im[x] = -im[x]; }
    }

    // Fused layer-3 RY(t3) + <Z> on bit 2:
    //   zq = cos(t3) * sum(p0 - p1)  -  sin(t3) * 2 * sum Re(a0 * conj(a1))
    float zd = 0.0f, zc = 0.0f;
#pragma unroll
    for (int x = 0; x < 32; x++) {
        if (!(x & 4)) {
            const int y = x | 4;
            zd += (re[x] * re[x] + im[x] * im[x]) - (re[y] * re[y] + im[y] * im[y]);
            zc += re[x] * re[y] + im[x] * im[y];
        }
    }
    const float zq = c3 * zd - 2.0f * s3 * zc;

    float contrib = qv ? hw[(NQ - 1) - q] * zq : 0.0f;

    // Wave-wide butterfly reduction (lanes >= 15 contribute 0).
#pragma unroll
    for (int off = 32; off >= 1; off >>= 1)
        contrib += __shfl_xor(contrib, off, 64);

    if (lane == 0 && bv)
        out[b] = contrib + hb[0];
}

extern "C" void kernel_launch(void* const* d_in, const int* in_sizes, int n_in,
                              void* d_out, int out_size, void* d_ws, size_t ws_size,
                              hipStream_t stream) {
    const float* sb    = (const float*)d_in[0]; // state_batch (512,15)
    const float* theta = (const float*)d_in[1]; // (45,)
    const float* hw    = (const float*)d_in[2]; // (1,15)
    const float* hb    = (const float*)d_in[3]; // (1,)
    float* out = (float*)d_out;                 // (512,) fp32

    const int batch = in_sizes[0] / NQ;
    const int blocks = (batch + 3) / 4;

    hipLaunchKernelGGL(HybridRegression_lightcone2_kernel,
                       dim3(blocks), dim3(256), 0, stream,
                       sb, theta, hw, hb, out, batch);
}